// Round 9
// baseline (683.686 us; speedup 1.0000x reference)
//
#include <hip/hip_runtime.h>

// Problem constants (fixed by reference)
#define R_   3
#define N_   50000
#define E_   400000
#define IN_  128
#define HID_ 64
#define C_   40
#define H_   3
#define NEG_SLOPE 0.2f

#define SCAN_CHUNK 1024
#define NCH  49      // ceil(N_/1024)
#define NCH2 64      // padded stride

// padded z-row strides (in halves): [3*Dd fp16 | 3*fp32 el | pad]
#define ZS1 200      // Dd=64: 192 + 6 + pad -> 400 B
#define ZS2 128      // Dd=40: 120 + 6 + pad -> 256 B

typedef _Float16 half_t;
typedef _Float16 f16x8 __attribute__((ext_vector_type(8)));
typedef _Float16 f16x4 __attribute__((ext_vector_type(4)));
typedef float float4v __attribute__((ext_vector_type(4)));

__device__ __forceinline__ float readlane_f(float v, int l) {
    return __int_as_float(__builtin_amdgcn_readlane(__float_as_int(v), l));
}

// ---------------- utility ----------------
__global__ void zero_kernel(float* __restrict__ p, size_t n) {
    size_t i = (size_t)blockIdx.x * blockDim.x + threadIdx.x;
    if (i < n) p[i] = 0.f;
}

// float -> half, vectorized x4 (n must be divisible by 4)
__global__ void cast_f2h_kernel(const float* __restrict__ in, half_t* __restrict__ outp, int n4) {
    int i = blockIdx.x * 256 + threadIdx.x;
    if (i < n4) {
        float4 v = ((const float4*)in)[i];
        f16x4 h;
        h[0] = (half_t)v.x; h[1] = (half_t)v.y;
        h[2] = (half_t)v.z; h[3] = (half_t)v.w;
        ((f16x4*)outp)[i] = h;
    }
}

// W: [R][K][Nc] fp32 -> Wt: [R][Nc][K] fp16 (tiny matrices)
__global__ void transcast_kernel(const float* __restrict__ W, half_t* __restrict__ Wt,
                                 int K, int Nc) {
    int idx = blockIdx.x * 256 + threadIdx.x;
    int total = R_ * K * Nc;
    if (idx < total) {
        int r = idx / (K * Nc);
        int rem = idx - r * K * Nc;
        int n = rem / K;
        int k = rem - n * K;
        Wt[idx] = (half_t)W[((size_t)r * K + k) * Nc + n];
    }
}

// ---------------- CSR build ----------------
__global__ void hist_kernel(const int* __restrict__ dst, int* __restrict__ deg) {
    int idx = blockIdx.x * 256 + threadIdx.x;
    if (idx < R_ * E_) {
        int r = idx / E_;
        atomicAdd(&deg[r * N_ + dst[idx]], 1);
    }
}

__global__ void scanA_kernel(const int* __restrict__ deg, int* __restrict__ bsum) {
    int r = blockIdx.y, ch = blockIdx.x, tid = threadIdx.x;
    int base = ch * SCAN_CHUNK + tid * 4;
    int s = 0;
    for (int j = 0; j < 4; ++j) {
        int i = base + j;
        if (i < N_) s += deg[r * N_ + i];
    }
    __shared__ int red[256];
    red[tid] = s; __syncthreads();
    for (int off = 128; off; off >>= 1) {
        if (tid < off) red[tid] += red[tid + off];
        __syncthreads();
    }
    if (tid == 0) bsum[r * NCH2 + ch] = red[0];
}

__global__ void scanB_kernel(int* __restrict__ bsum) {
    int t = threadIdx.x;
    if (t < R_) {
        int run = 0;
        for (int c = 0; c < NCH; ++c) {
            int v = bsum[t * NCH2 + c];
            bsum[t * NCH2 + c] = run;
            run += v;
        }
    }
}

__global__ void scanC_kernel(const int* __restrict__ deg, const int* __restrict__ bsum,
                             int* __restrict__ rowptr, int* __restrict__ cursor) {
    int r = blockIdx.y, ch = blockIdx.x, tid = threadIdx.x;
    int base = ch * SCAN_CHUNK + tid * 4;
    int v[4]; int s = 0;
    for (int j = 0; j < 4; ++j) {
        int i = base + j;
        v[j] = (i < N_) ? deg[r * N_ + i] : 0;
        s += v[j];
    }
    __shared__ int buf[256];
    buf[tid] = s; __syncthreads();
    for (int off = 1; off < 256; off <<= 1) {
        int t2 = (tid >= off) ? buf[tid - off] : 0;
        __syncthreads();
        buf[tid] += t2;
        __syncthreads();
    }
    int excl = buf[tid] - s + bsum[r * NCH2 + ch];
    int run = excl;
    for (int j = 0; j < 4; ++j) {
        int i = base + j;
        if (i < N_) {
            rowptr[r * (N_ + 1) + i] = run;
            cursor[r * N_ + i] = run;
            run += v[j];
        }
    }
    if (ch == 0 && tid == 0) rowptr[r * (N_ + 1) + N_] = E_;
}

__global__ void fill_kernel(const int* __restrict__ src, const int* __restrict__ dst,
                            int* __restrict__ cursor, int* __restrict__ csr_src) {
    int idx = blockIdx.x * 256 + threadIdx.x;
    if (idx < R_ * E_) {
        int r = idx / E_;
        int pos = atomicAdd(&cursor[r * N_ + dst[idx]], 1);
        csr_src[(size_t)r * E_ + pos] = src[idx];
    }
}

// ---------------- MFMA GEMM: Z[r] = A @ Bt[r]^T (strided z rows) ----------------
template <int K, int ZS>
__global__ __launch_bounds__(256) void mfma_gemm_kernel(
        const half_t* __restrict__ A, const half_t* __restrict__ Bt,
        half_t* __restrict__ Z, int M, int Nc) {
    int r = blockIdx.z;
    int wave = threadIdx.x >> 6, lane = threadIdx.x & 63;
    int lrow = lane & 15, lq = lane >> 4;
    int rowA = blockIdx.x * 64 + wave * 16 + lrow;
    int col0 = blockIdx.y * 64;
    const half_t* Btr = Bt + (size_t)r * Nc * K;
    const half_t* aP = A + (size_t)rowA * K + lq * 8;
    bool arow_ok = (rowA < M);
    f16x8 zv8 = {};
    float4v acc[4] = {};
    #pragma unroll
    for (int k0 = 0; k0 < K; k0 += 32) {
        f16x8 af = arow_ok ? *(const f16x8*)(aP + k0) : zv8;
        #pragma unroll
        for (int ct = 0; ct < 4; ++ct) {
            int col = col0 + ct * 16 + lrow;
            f16x8 bf = (col < Nc) ? *(const f16x8*)(Btr + (size_t)col * K + lq * 8 + k0) : zv8;
            acc[ct] = __builtin_amdgcn_mfma_f32_16x16x32_f16(af, bf, acc[ct], 0, 0, 0);
        }
    }
    half_t* Zr = Z + (size_t)r * N_ * ZS;
    int rbase = blockIdx.x * 64 + wave * 16 + lq * 4;
    #pragma unroll
    for (int ct = 0; ct < 4; ++ct) {
        int col = col0 + ct * 16 + lrow;
        if (col >= Nc) continue;
        #pragma unroll
        for (int g = 0; g < 4; ++g) {
            int row = rbase + g;
            if (row < M) Zr[(size_t)row * ZS + col] = (half_t)acc[ct][g];
        }
    }
}

// ---------------- attention logits (el -> z-row tail, er -> buffer) ----------------
template <int Dd, int ZS>
__global__ __launch_bounds__(256) void attn_kernel(
        half_t* __restrict__ z, const float* __restrict__ al,
        const float* __restrict__ ar, float* __restrict__ er) {
    int wid = blockIdx.x * 4 + (threadIdx.x >> 6);
    int lane = threadIdx.x & 63;
    if (wid >= R_ * N_) return;
    int r = wid / N_;
    half_t* zr = z + (size_t)wid * ZS;
    float* elt = (float*)(zr + 3 * Dd);
    for (int h = 0; h < H_; ++h) {
        float v = (lane < Dd) ? (float)zr[h * Dd + lane] : 0.f;
        float a = (lane < Dd) ? al[(r * H_ + h) * Dd + lane] : 0.f;
        float b = (lane < Dd) ? ar[(r * H_ + h) * Dd + lane] : 0.f;
        float p = v * a, q = v * b;
        for (int off = 32; off; off >>= 1) {
            p += __shfl_xor(p, off);
            q += __shfl_xor(q, off);
        }
        if (lane == 0) {
            elt[h] = p;
            er[(size_t)wid * H_ + h] = q;
        }
    }
}

// ---------------- fused softmax + gather + aggregate (v5: lane = out dim) --------
// One wave per (r,dst). Phase A per 16-edge chunk: lane (k=lane&15, h=lane>>4,
// h<3) computes c=exp(leaky(el+er)) — 48 coefficients batched in ~8 instrs.
// Phase B: per edge, c0/c1/c2 and row offset broadcast via readlane (SGPR),
// lane d does 3 coalesced 2B loads + 3 fma. NO redistribution: lane owns
// output col d. Epilogue: 4-step l-butterfly per head group, 3 readlane+rcp,
// per-head relu, ONE coalesced atomicAdd.
template <int Dd, int ZS, bool RELU>
__global__ __launch_bounds__(256) void agg8_kernel(
        const int* __restrict__ rowptr, const int* __restrict__ csr_src,
        const half_t* __restrict__ z, const float* __restrict__ er,
        const float* __restrict__ bias, float* __restrict__ out, float scale) {
    constexpr int ROWH = 3 * Dd;        // z halves per row (el tail after)
    int wid = blockIdx.x * 4 + (threadIdx.x >> 6);
    int lane = threadIdx.x & 63;
    if (wid >= R_ * N_) return;
    int r = wid / N_, n = wid - r * N_;
    int start = rowptr[r * (N_ + 1) + n];
    int end   = rowptr[r * (N_ + 1) + n + 1];
    const int* cs = csr_src + (size_t)r * E_;
    const half_t* zr = z + (size_t)r * N_ * ZS;   // uniform base
    int k = lane & 15, hg = lane >> 4;            // phase-A mapping
    bool aact = hg < 3;
    float erv = aact ? er[(size_t)wid * H_ + hg] : 0.f;
    int ll = (lane < Dd) ? lane : 0;              // safe load index
    float lpart = 0.f;
    float a0 = 0.f, a1 = 0.f, a2 = 0.f;
    for (int i = start; i < end; i += 16) {
        int rem = end - i; if (rem > 16) rem = 16;
        // ---- phase A: batched coefficients ----
        int ei = i + k; if (ei > end - 1) ei = end - 1;
        int o = cs[ei] * ZS;
        float c = 0.f;
        if (aact && k < rem) {
            float e = ((const float*)(zr + o + ROWH))[hg] + erv;
            e = fmaxf(e, NEG_SLOPE * e);
            c = __expf(e);
        }
        lpart += c;
        // ---- phase B: value accumulation, lane = out dim ----
        for (int kk = 0; kk < rem; ++kk) {
            int ok = __builtin_amdgcn_readlane(o, kk);
            float c0 = readlane_f(c, kk);
            float c1 = readlane_f(c, 16 + kk);
            float c2 = readlane_f(c, 32 + kk);
            const half_t* zrow = zr + ok;
            a0 += c0 * (float)zrow[ll];
            a1 += c1 * (float)zrow[Dd + ll];
            a2 += c2 * (float)zrow[2 * Dd + ll];
        }
    }
    // ---- l butterfly within 16-lane groups ----
    int gb = lane & 48;
    #pragma unroll
    for (int mm = 1; mm <= 8; mm <<= 1)
        lpart += __shfl(lpart, gb | ((lane & 15) ^ mm));
    float l0 = readlane_f(lpart, 0);
    float l1 = readlane_f(lpart, 16);
    float l2 = readlane_f(lpart, 32);
    float li0 = (l0 > 0.f) ? 1.f / l0 : 0.f;
    float li1 = (l1 > 0.f) ? 1.f / l1 : 0.f;
    float li2 = (l2 > 0.f) ? 1.f / l2 : 0.f;
    if (lane < Dd) {
        const float* br = bias + r * ROWH;
        float v0 = a0 * li0 + br[lane];
        float v1 = a1 * li1 + br[Dd + lane];
        float v2 = a2 * li2 + br[2 * Dd + lane];
        if (RELU) {
            v0 = fmaxf(v0, 0.f); v1 = fmaxf(v1, 0.f); v2 = fmaxf(v2, 0.f);
        }
        atomicAdd(&out[(size_t)n * Dd + lane], (v0 + v1 + v2) * scale);
    }
}

// ---------------- launch ----------------
static inline size_t align256(size_t x) { return (x + 255) & ~(size_t)255; }

extern "C" void kernel_launch(void* const* d_in, const int* in_sizes, int n_in,
                              void* d_out, int out_size, void* d_ws, size_t ws_size,
                              hipStream_t stream) {
    const float* feat = (const float*)d_in[0];
    const int*   src  = (const int*)d_in[1];
    const int*   dst  = (const int*)d_in[2];
    const float* W1   = (const float*)d_in[3];
    const float* al1  = (const float*)d_in[4];
    const float* ar1  = (const float*)d_in[5];
    const float* b1   = (const float*)d_in[6];
    const float* W2   = (const float*)d_in[7];
    const float* al2  = (const float*)d_in[8];
    const float* ar2  = (const float*)d_in[9];
    const float* b2   = (const float*)d_in[10];
    float* out = (float*)d_out;

    // workspace carve (zbuf sized for ZS1; layer 2 reuses with ZS2)
    char* ws = (char*)d_ws;
    size_t off = 0;
    half_t* zbuf = (half_t*)(ws + off); off += align256((size_t)R_ * N_ * ZS1 * 2);
    half_t* featH = (half_t*)(ws + off); off += align256((size_t)N_ * IN_ * 2);
    half_t* h1h  = (half_t*)(ws + off); off += align256((size_t)N_ * HID_ * 2);
    half_t* W1t  = (half_t*)(ws + off); off += align256((size_t)R_ * (H_ * HID_) * IN_ * 2);
    half_t* W2t  = (half_t*)(ws + off); off += align256((size_t)R_ * (H_ * C_) * HID_ * 2);
    float* er   = (float*)(ws + off); off += align256((size_t)R_ * N_ * H_ * 4);
    float* h1f  = (float*)(ws + off); off += align256((size_t)N_ * HID_ * 4);
    int* deg    = (int*)(ws + off);   off += align256((size_t)R_ * N_ * 4);
    int* rowptr = (int*)(ws + off);   off += align256((size_t)R_ * (N_ + 1) * 4);
    int* cursor = (int*)(ws + off);   off += align256((size_t)R_ * N_ * 4);
    int* bsum   = (int*)(ws + off);   off += align256((size_t)R_ * NCH2 * 4);
    int* csr    = (int*)(ws + off);   off += align256((size_t)R_ * E_ * 4);
    (void)ws_size; (void)n_in; (void)in_sizes; (void)out_size;

    const int EDGE_BLOCKS = (R_ * E_ + 255) / 256;     // 4688
    const int ROW_TILES = (N_ + 63) / 64;              // 782
    const int NODE_BLOCKS = (R_ * N_ + 255) / 256;     // 586
    const int WAVE_BLOCKS = (R_ * N_) / 4;             // 37500

    // ---- input casts / weight transposes ----
    cast_f2h_kernel<<<(N_ * IN_ / 4 + 255) / 256, 256, 0, stream>>>(feat, featH, N_ * IN_ / 4);
    transcast_kernel<<<(R_ * IN_ * (H_ * HID_) + 255) / 256, 256, 0, stream>>>(W1, W1t, IN_, H_ * HID_);
    transcast_kernel<<<(R_ * HID_ * (H_ * C_) + 255) / 256, 256, 0, stream>>>(W2, W2t, HID_, H_ * C_);

    // ---- CSR build (shared by both layers) ----
    zero_kernel<<<NODE_BLOCKS, 256, 0, stream>>>((float*)deg, (size_t)R_ * N_);
    hist_kernel<<<EDGE_BLOCKS, 256, 0, stream>>>(dst, deg);
    scanA_kernel<<<dim3(NCH, R_), 256, 0, stream>>>(deg, bsum);
    scanB_kernel<<<1, 64, 0, stream>>>(bsum);
    scanC_kernel<<<dim3(NCH, R_), 256, 0, stream>>>(deg, bsum, rowptr, cursor);
    fill_kernel<<<EDGE_BLOCKS, 256, 0, stream>>>(src, dst, cursor, csr);

    // ---- layer 1: IN -> H*HID, relu ----
    mfma_gemm_kernel<IN_, ZS1><<<dim3(ROW_TILES, 3, R_), 256, 0, stream>>>(
        featH, W1t, zbuf, N_, H_ * HID_);
    attn_kernel<HID_, ZS1><<<WAVE_BLOCKS, 256, 0, stream>>>(zbuf, al1, ar1, er);
    zero_kernel<<<((size_t)N_ * HID_ + 255) / 256, 256, 0, stream>>>(h1f, (size_t)N_ * HID_);
    agg8_kernel<HID_, ZS1, true><<<WAVE_BLOCKS, 256, 0, stream>>>(
        rowptr, csr, zbuf, er, b1, h1f, 1.f / (H_ * R_));
    cast_f2h_kernel<<<(N_ * HID_ / 4 + 255) / 256, 256, 0, stream>>>(h1f, h1h, N_ * HID_ / 4);

    // ---- layer 2: HID -> H*C, no relu ----
    mfma_gemm_kernel<HID_, ZS2><<<dim3(ROW_TILES, 2, R_), 256, 0, stream>>>(
        h1h, W2t, zbuf, N_, H_ * C_);
    attn_kernel<C_, ZS2><<<WAVE_BLOCKS, 256, 0, stream>>>(zbuf, al2, ar2, er);
    zero_kernel<<<((size_t)N_ * C_ + 255) / 256, 256, 0, stream>>>(out, (size_t)N_ * C_);
    agg8_kernel<C_, ZS2, false><<<WAVE_BLOCKS, 256, 0, stream>>>(
        rowptr, csr, zbuf, er, b2, out, 1.f / (H_ * R_));
}